// Round 15
// baseline (48.717 us; speedup 1.0000x reference)
//
#include <hip/hip_runtime.h>

#define NB 16
#define NN 256
#define NH 128
#define NE 16

typedef float v4f    __attribute__((ext_vector_type(4)));
typedef float f32x16 __attribute__((ext_vector_type(16)));
typedef short bf16x8 __attribute__((ext_vector_type(8)));
typedef unsigned int uint;

constexpr long long EF_ELEMS = (long long)NB * NN * NN * NE; // 16777216

// ws layout (floats): Mt[512] | c2[32] | Pi[4096*32] | Pj[4096*32]

// pack two f32 into bf16 pair (hi) + residual pair (lo), RNE-consistent
__device__ __forceinline__ void pk_hilo(float x0, float x1, uint& hi, uint& lo) {
    uint h;
    asm("v_cvt_pk_bf16_f32 %0, %1, %2" : "=v"(h) : "v"(x0), "v"(x1));
    const float h0 = __uint_as_float(h << 16);
    const float h1 = __uint_as_float(h & 0xFFFF0000u);
    uint l;
    asm("v_cvt_pk_bf16_f32 %0, %1, %2" : "=v"(l) : "v"(x0 - h0), "v"(x1 - h1));
    hi = h; lo = l;
}

// DPP-based add (VALU, not DS pipe); CTRL must be a compile-time constant
template <int CTRL>
__device__ __forceinline__ float dpp_add(float x) {
    int y = __builtin_amdgcn_update_dpp(0, __float_as_int(x), CTRL, 0xF, 0xF, true);
    return x + __int_as_float(y);
}
// sum over the 32-lane half (lanes 0-31 or 32-63); result in every lane of the half
__device__ __forceinline__ float halfsum32(float v) {
    v = dpp_add<0xB1>(v);    // quad_perm [1,0,3,2]  (xor1)
    v = dpp_add<0x4E>(v);    // quad_perm [2,3,0,1]  (xor2)
    v = dpp_add<0x124>(v);   // row_ror:4
    v = dpp_add<0x128>(v);   // row_ror:8  -> 16-lane row sum
    v += __shfl_xor(v, 16);  // combine the two rows of the half
    return v;
}

// ==================== A: fused prep (block 2048) + proj (blocks 0..2047) ============
__global__ __launch_bounds__(256) void k_prep_proj3(
    const float* __restrict__ node, const float* __restrict__ uW1,
    const float* __restrict__ dW2, const float* __restrict__ db2,
    const float* __restrict__ ub1,
    float* __restrict__ Mt, float* __restrict__ c2,
    float* __restrict__ Pi, float* __restrict__ Pj)
{
    const int t = threadIdx.x;
    if (blockIdx.x == 2048) {
        // M[k][c] = sum_e dW2[k][e] * uW1[256+e][c]; store transposed Mt[c][k]
        __shared__ float sM[512];
        for (int i = t; i < 512; i += 256) {
            const int k = i >> 5, c = i & 31;
            float s = 0.f;
#pragma unroll
            for (int e = 0; e < 16; ++e)
                s = fmaf(dW2[k * 16 + e], uW1[(256 + e) * 32 + c], s);
            sM[i] = s;
        }
        __syncthreads();
        for (int i = t; i < 512; i += 256)
            Mt[(i & 31) * 16 + (i >> 5)] = sM[i];
        if (t < 32) {
            float s2 = ub1[t];
#pragma unroll
            for (int e = 0; e < 16; ++e)
                s2 = fmaf(db2[e], uW1[(256 + e) * 32 + t], s2);
            c2[t] = s2;
        }
    } else {
        // proj: 2 rows/block, k-split x2 -> 64-FMA chains, shfl reduce
        const int r    = t >> 7;
        const int half = (t >> 6) & 1;    // 0 -> Pi, 1 -> Pj
        const int ks   = (t >> 5) & 1;
        const int c    = t & 31;
        const int row  = blockIdx.x * 2 + r;
        __shared__ float nrow[2][128];
        nrow[r][t & 127] = node[(size_t)row * 128 + (t & 127)];
        __syncthreads();
        const float* w = uW1 + half * 128 * 32 + c;
        const int k0 = ks * 64;
        float s = 0.f;
#pragma unroll 8
        for (int k = 0; k < 64; ++k)
            s = fmaf(nrow[r][k0 + k], w[(size_t)(k0 + k) * 32], s);
        s += __shfl_xor(s, 32);
        if (!(t & 32))
            (half ? Pj : Pi)[(size_t)row * 32 + c] = s;
    }
}

// ==================== B: edge — dist-MLP via MFMA, 32-edge passes ====================
// Lane (e32=lane&31, s=lane>>5). Per pass: 32 edges; D[ch][edge] = Mt·T via 3 MFMAs
// (hi/lo), D layout (verified): col=lane&31=edge, row=(m&3)+8(m>>2)+4s = channel.
// Lane holds 16 of 32 channels; partner lane^32 the rest -> LN = 1 shfl_xor(32).
// uW2 MFMA: e_out rows 0-15 (16-31 zero-pad); B-frag packed from local h, A-frags
// loaded with the SAME channel-pair order -> K-slot mapping cancels.
__global__ __launch_bounds__(256) void k_edge11(
    const float* __restrict__ dist, const int* __restrict__ visited,
    const float* __restrict__ ln_g, const float* __restrict__ ln_b,
    const float* __restrict__ uW2, const float* __restrict__ ub2,
    const float* __restrict__ dW1, const float* __restrict__ db1,
    const float* __restrict__ Mt, const float* __restrict__ c2g,
    const float* __restrict__ Pi, const float* __restrict__ Pj,
    const float* __restrict__ nW1, const float* __restrict__ nb1,
    const float* __restrict__ nW2, const float* __restrict__ nb2,
    float* __restrict__ ef_out, float* __restrict__ msg_out)
{
    const int row0 = blockIdx.x * 4;      // 4 rows, same batch b
    const int b = row0 >> 8;
    const int j = threadIdx.x;

    __shared__ float red2[4][4][16];      // 1 KB
    __shared__ float pool_s[4][16];
    __shared__ float hid_s[4][64];

    const int lane = j & 63, wv = j >> 6;
    const int e32 = lane & 31;            // edge-in-pass / D col / A row (e_out or ch)
    const int s   = lane >> 5;            // K-half / row-offset selector

    // ---- once-per-block register fragments ----
    // Mt fragment (A of T@M): lane ch=e32, k = 8s..8s+7
    bf16x8 Mth, Mtl;
    {
        union { uint u[4]; bf16x8 v; } H, L;
        const float4 mA = *reinterpret_cast<const float4*>(Mt + e32 * 16 + 8 * s);
        const float4 mB = *reinterpret_cast<const float4*>(Mt + e32 * 16 + 8 * s + 4);
        const float mv[8] = {mA.x, mA.y, mA.z, mA.w, mB.x, mB.y, mB.z, mB.w};
#pragma unroll
        for (int i = 0; i < 4; ++i) pk_hilo(mv[2 * i], mv[2 * i + 1], H.u[i], L.u[i]);
        Mth = H.v; Mtl = L.v;
    }
    // uW2 fragments (A of h@uW2), channel-pair order matches B packing below
    bf16x8 A0h, A0l, A1h, A1l;
    {
#pragma unroll
        for (int Hh = 0; Hh < 2; ++Hh) {
            union { uint u[4]; bf16x8 v; } H, L;
            const int base = 16 * Hh + 4 * s;
            const int cpr[8] = {base, base + 1, base + 2, base + 3,
                                base + 8, base + 9, base + 10, base + 11};
            float w[8];
#pragma unroll
            for (int i = 0; i < 8; ++i)
                w[i] = (e32 < 16) ? uW2[cpr[i] * 16 + e32] : 0.f;
#pragma unroll
            for (int i = 0; i < 4; ++i) pk_hilo(w[2 * i], w[2 * i + 1], H.u[i], L.u[i]);
            if (Hh == 0) { A0h = H.v; A0l = L.v; } else { A1h = H.v; A1l = L.v; }
        }
    }
    // dW1/db1 slices for this lane's K-half
    float aK[8], bK[8];
    {
        const float4 aA = *reinterpret_cast<const float4*>(dW1 + 8 * s);
        const float4 aB = *reinterpret_cast<const float4*>(dW1 + 8 * s + 4);
        const float4 bA = *reinterpret_cast<const float4*>(db1 + 8 * s);
        const float4 bB = *reinterpret_cast<const float4*>(db1 + 8 * s + 4);
        aK[0]=aA.x; aK[1]=aA.y; aK[2]=aA.z; aK[3]=aA.w;
        aK[4]=aB.x; aK[5]=aB.y; aK[6]=aB.z; aK[7]=aB.w;
        bK[0]=bA.x; bK[1]=bA.y; bK[2]=bA.z; bK[3]=bA.w;
        bK[4]=bB.x; bK[5]=bB.y; bK[6]=bB.z; bK[7]=bB.w;
    }
    // ub2 C-init (e_out rows; rows>=16 are pad)
    f32x16 ub2i;
    {
        const float4 uA = *reinterpret_cast<const float4*>(ub2 + 4 * s);
        const float4 uB = *reinterpret_cast<const float4*>(ub2 + 8 + 4 * s);
        ub2i[0]=uA.x; ub2i[1]=uA.y; ub2i[2]=uA.z; ub2i[3]=uA.w;
        ub2i[4]=uB.x; ub2i[5]=uB.y; ub2i[6]=uB.z; ub2i[7]=uB.w;
#pragma unroll
        for (int m = 8; m < 16; ++m) ub2i[m] = 0.f;
    }
    // LN affine at this lane's channel rows: offsets {4s, 8+4s, 16+4s, 24+4s}
    float gl[16], bl[16];
#pragma unroll
    for (int q = 0; q < 4; ++q) {
        const int off = q * 8 + 4 * s;
        const float4 gv = *reinterpret_cast<const float4*>(ln_g + off);
        const float4 bv = *reinterpret_cast<const float4*>(ln_b + off);
        gl[q*4+0]=gv.x; gl[q*4+1]=gv.y; gl[q*4+2]=gv.z; gl[q*4+3]=gv.w;
        bl[q*4+0]=bv.x; bl[q*4+1]=bv.y; bl[q*4+2]=bv.z; bl[q*4+3]=bv.w;
    }

    float scv[4];
#pragma unroll
    for (int r = 0; r < 4; ++r) scv[r] = visited[row0 + r] ? 0.5f : 1.0f;

    for (int r = 0; r < 4; ++r) {
        const int row = row0 + r;
        const float scale = scv[r];

        // C-init for T@M: c2 + Pi at this lane's channel rows
        f32x16 cin;
#pragma unroll
        for (int q = 0; q < 4; ++q) {
            const int off = q * 8 + 4 * s;
            const float4 pv = *reinterpret_cast<const float4*>(Pi + (size_t)row * 32 + off);
            const float4 cv = *reinterpret_cast<const float4*>(c2g + off);
            cin[q*4+0] = pv.x + cv.x; cin[q*4+1] = pv.y + cv.y;
            cin[q*4+2] = pv.z + cv.z; cin[q*4+3] = pv.w + cv.w;
        }

        float accsum[8];
#pragma unroll
        for (int m = 0; m < 8; ++m) accsum[m] = 0.f;

#pragma unroll
        for (int p = 0; p < 2; ++p) {
            const int edge = wv * 64 + p * 32 + e32;
            const float d = dist[(size_t)row * NN + edge];

            // T fragment: t_k = relu(a_k d + b_k), hi/lo split
            bf16x8 Th, Tl;
            {
                union { uint u[4]; bf16x8 v; } H, L;
                float tv[8];
#pragma unroll
                for (int i = 0; i < 8; ++i)
                    tv[i] = fmaxf(fmaf(aK[i], d, bK[i]), 0.f);
#pragma unroll
                for (int i = 0; i < 4; ++i) pk_hilo(tv[2*i], tv[2*i+1], H.u[i], L.u[i]);
                Th = H.v; Tl = L.v;
            }

            // D[ch][edge] = Mt.T + (c2+Pi): 3 MFMAs (drop lo*lo)
            f32x16 acc = __builtin_amdgcn_mfma_f32_32x32x16_bf16(Mth, Th, cin, 0, 0, 0);
            acc = __builtin_amdgcn_mfma_f32_32x32x16_bf16(Mtl, Th, acc, 0, 0, 0);
            acc = __builtin_amdgcn_mfma_f32_32x32x16_bf16(Mth, Tl, acc, 0, 0, 0);

            // + Pj -> pre (16 local channels)
            const float* pjp = Pj + ((size_t)(b * NN) + edge) * 32;
            float pre[16];
#pragma unroll
            for (int q = 0; q < 4; ++q) {
                const int off = q * 8 + 4 * s;
                const float4 pv = *reinterpret_cast<const float4*>(pjp + off);
                pre[q*4+0] = acc[q*4+0] + pv.x; pre[q*4+1] = acc[q*4+1] + pv.y;
                pre[q*4+2] = acc[q*4+2] + pv.z; pre[q*4+3] = acc[q*4+3] + pv.w;
            }

            // LayerNorm: local 16-sums + one shfl_xor(32)
            float s1 = 0.f, qq = 0.f;
#pragma unroll
            for (int m = 0; m < 16; ++m) { s1 += pre[m]; qq = fmaf(pre[m], pre[m], qq); }
            s1 += __shfl_xor(s1, 32);
            qq += __shfl_xor(qq, 32);
            const float mu   = s1 * (1.f / 32.f);
            const float var  = fmaf(-mu, mu, qq * (1.f / 32.f));
            const float rstd = rsqrtf(fmaxf(var, 0.f) + 1e-5f);

            float h[16];
#pragma unroll
            for (int m = 0; m < 16; ++m)
                h[m] = fmaxf(fmaf((pre[m] - mu) * rstd, gl[m], bl[m]), 0.f);

            // B fragments for h@uW2 (pair order matches A-frag loads)
            union { uint u[4]; bf16x8 v; } B0, B1;
#pragma unroll
            for (int i = 0; i < 4; ++i) {
                uint rr;
                asm("v_cvt_pk_bf16_f32 %0, %1, %2" : "=v"(rr) : "v"(h[2*i]), "v"(h[2*i+1]));
                B0.u[i] = rr;
            }
#pragma unroll
            for (int i = 0; i < 4; ++i) {
                uint rr;
                asm("v_cvt_pk_bf16_f32 %0, %1, %2" : "=v"(rr) : "v"(h[8+2*i]), "v"(h[8+2*i+1]));
                B1.u[i] = rr;
            }

            f32x16 ef = __builtin_amdgcn_mfma_f32_32x32x16_bf16(A0h, B0.v, ub2i, 0, 0, 0);
            ef = __builtin_amdgcn_mfma_f32_32x32x16_bf16(A0l, B0.v, ef, 0, 0, 0);
            ef = __builtin_amdgcn_mfma_f32_32x32x16_bf16(A1h, B1.v, ef, 0, 0, 0);
            ef = __builtin_amdgcn_mfma_f32_32x32x16_bf16(A1l, B1.v, ef, 0, 0, 0);

            // scale + store (e_out rows 4s..4s+3 and 8+4s..8+4s+3); rows>=16 = pad
            const float e0 = ef[0]*scale, e1 = ef[1]*scale, e2 = ef[2]*scale, e3 = ef[3]*scale;
            const float e4 = ef[4]*scale, e5 = ef[5]*scale, e6 = ef[6]*scale, e7 = ef[7]*scale;
            float* op = ef_out + ((size_t)row * NN + edge) * 16;
            *reinterpret_cast<v4f*>(op + 4 * s)     = (v4f){e0, e1, e2, e3};
            *reinterpret_cast<v4f*>(op + 8 + 4 * s) = (v4f){e4, e5, e6, e7};
            accsum[0] += e0; accsum[1] += e1; accsum[2] += e2; accsum[3] += e3;
            accsum[4] += e4; accsum[5] += e5; accsum[6] += e6; accsum[7] += e7;
        }

        // pooled partial: sum over the 32 edge-lanes of this half (DPP + 1 shfl)
#pragma unroll
        for (int m = 0; m < 8; ++m) accsum[m] = halfsum32(accsum[m]);
        if (e32 == 0) {
            *reinterpret_cast<v4f*>(&red2[r][wv][4 * s])     = (v4f){accsum[0], accsum[1], accsum[2], accsum[3]};
            *reinterpret_cast<v4f*>(&red2[r][wv][8 + 4 * s]) = (v4f){accsum[4], accsum[5], accsum[6], accsum[7]};
        }
    }

    __syncthreads();   // red2 complete

    // pooled means (4 rows x 16 e)
    if (j < 64) {
        const int r = j >> 4, e = j & 15;
        pool_s[r][e] = (red2[r][0][e] + red2[r][1][e] + red2[r][2][e] + red2[r][3][e])
                       * (1.f / 256.f);
    }
    __syncthreads();

    // node MLP layer 1 (4 rows x 64 hidden)
    {
        const int r = j >> 6, u = j & 63;
        float sum = nb1[u];
#pragma unroll
        for (int e = 0; e < 16; ++e)
            sum = fmaf(pool_s[r][e], nW1[e * 64 + u], sum);
        hid_s[r][u] = fmaxf(sum, 0.f);
    }
    __syncthreads();

    // node MLP layer 2 (4x128 outputs, 2 passes)
#pragma unroll
    for (int p = 0; p < 2; ++p) {
        const int idx = p * 256 + j;
        const int r = idx >> 7, o = idx & 127;
        float sum = nb2[o];
#pragma unroll 8
        for (int q = 0; q < 64; ++q)
            sum = fmaf(hid_s[r][q], nW2[q * 128 + o], sum);
        msg_out[(size_t)(row0 + r) * 128 + o] = sum;
    }
}

extern "C" void kernel_launch(void* const* d_in, const int* in_sizes, int n_in,
                              void* d_out, int out_size, void* d_ws, size_t ws_size,
                              hipStream_t stream)
{
    const float* node    = (const float*)d_in[0];
    const float* dist    = (const float*)d_in[1];
    const int*   visited = (const int*)  d_in[2];
    const float* dW1     = (const float*)d_in[3];
    const float* db1     = (const float*)d_in[4];
    const float* dW2     = (const float*)d_in[5];
    const float* db2     = (const float*)d_in[6];
    const float* uW1     = (const float*)d_in[7];
    const float* ub1     = (const float*)d_in[8];
    const float* ln_g    = (const float*)d_in[9];
    const float* ln_b    = (const float*)d_in[10];
    const float* uW2     = (const float*)d_in[11];
    const float* ub2     = (const float*)d_in[12];
    const float* nW1     = (const float*)d_in[13];
    const float* nb1     = (const float*)d_in[14];
    const float* nW2     = (const float*)d_in[15];
    const float* nb2     = (const float*)d_in[16];

    float* ws   = (float*)d_ws;
    float* Mt   = ws;                    // 512
    float* c2   = ws + 512;              // 32
    float* Pi   = ws + 544;              // 4096*32
    float* Pj   = Pi + 4096 * 32;        // 4096*32

    float* out = (float*)d_out;
    float* msg = out + EF_ELEMS;

    hipLaunchKernelGGL(k_prep_proj3, dim3(2049), dim3(256), 0, stream,
                       node, uW1, dW2, db2, ub1, Mt, c2, Pi, Pj);
    hipLaunchKernelGGL(k_edge11, dim3(1024), dim3(256), 0, stream,
                       dist, visited, ln_g, ln_b, uW2, ub2, dW1, db1, Mt, c2, Pi, Pj,
                       nW1, nb1, nW2, nb2, out, msg);
}